// Round 7
// baseline (277.731 us; speedup 1.0000x reference)
//
#include <hip/hip_runtime.h>

#define DEV __device__ __forceinline__

constexpr int N = 50000;
constexpr int E = 500000;
constexpr int D = 128;
constexpr int DFF = 256;
constexpr int NBANK = 64;  // stats contention spread

typedef __attribute__((ext_vector_type(8))) short bfrag8;
typedef __attribute__((ext_vector_type(4))) float f32x4;

// ---------- helpers ----------
DEV unsigned short f2b(float f) {
    unsigned u = __float_as_uint(f);
    unsigned r = (u + 0x7FFFu + ((u >> 16) & 1u)) >> 16;
    return (unsigned short)r;
}
DEV unsigned pack2(float a, float b) {
    return (unsigned)f2b(a) | ((unsigned)f2b(b) << 16);
}
DEV float b2f(unsigned short v) { return __uint_as_float(((unsigned)v) << 16); }
DEV float2 ld2b(const unsigned short* p) {
    unsigned u = *(const unsigned*)p;
    float2 r;
    r.x = __uint_as_float(u << 16);
    r.y = __uint_as_float(u & 0xFFFF0000u);
    return r;
}

// score = clip(dot/4, +-5); fold 0.25*log2e into Q, clip at 5*log2e, use exp2
constexpr float QSCALE = 0.36067376022224085f;  // 0.25 * log2(e)
constexpr float CLIP2 = 7.2134752044448170f;    // 5 * log2(e)

// ---------- workspace layout (bytes) ----------
constexpr size_t AL(size_t x) { return (x + 511) & ~(size_t)511; }
constexpr size_t OFF_COUNTS = 0;                                   // N int
constexpr size_t OFF_CURSORS = AL(OFF_COUNTS + (size_t)N * 4);     // N int
constexpr size_t OFF_BANK1 = AL(OFF_CURSORS + (size_t)N * 4);      // NBANK*256 f
constexpr size_t OFF_BANK2 = AL(OFF_BANK1 + NBANK * 256 * 4);      // NBANK*256 f
constexpr size_t OFF_DONE = OFF_BANK2 + NBANK * 256 * 4;           // 1 int (+pad)
constexpr size_t ZERO_END = OFF_DONE + 512;                        // zeroed by prep_w
constexpr size_t ZW = ZERO_END / 4;                                // words to zero
constexpr size_t OFF_OFFS = AL(ZERO_END);                          // N int
constexpr size_t OFF_BSUM = AL(OFF_OFFS + (size_t)N * 4);          // 256 int
constexpr size_t OFF_BPREF = AL(OFF_BSUM + 1024);                  // 256 int
constexpr size_t OFF_SS1 = AL(OFF_BPREF + 1024);                   // 256 f
constexpr size_t OFF_SS2 = AL(OFF_SS1 + 1024);                     // 256 f
constexpr size_t OFF_B1P = AL(OFF_SS2 + 1024);                     // 256 f
constexpr size_t OFF_CSR = AL(OFF_B1P + 1024);                     // E int
// weights in MFMA fragment-major order: frag[nt][kb][lane][8]
constexpr size_t OFF_WQKVP = AL(OFF_CSR + (size_t)E * 4);          // 3*16384 bf16
constexpr size_t OFF_WOP = AL(OFF_WQKVP + 49152 * 2);              // 16384 bf16
constexpr size_t OFF_W1PF = AL(OFF_WOP + 16384 * 2);               // 32768 f32 (pre-scale)
constexpr size_t OFF_W1P = AL(OFF_W1PF + 32768 * 4);               // 32768 bf16 (scaled)
constexpr size_t OFF_W2P = AL(OFF_W1P + 32768 * 2);                // 32768 bf16
constexpr size_t OFF_Q = AL(OFF_W2P + 32768 * 2);                  // N*128 bf16 (pre-scaled)
constexpr size_t OFF_KV = AL(OFF_Q + (size_t)N * 128 * 2);         // N*256 bf16, K|V interleaved
constexpr size_t OFF_AGG = AL(OFF_KV + (size_t)N * 256 * 2);       // N*128 bf16
constexpr size_t OFF_Y = AL(OFF_AGG + (size_t)N * 128 * 2);        // N*128 bf16
constexpr size_t OFF_T = AL(OFF_Y + (size_t)N * 128 * 2);          // N*128 bf16
constexpr size_t OFF_XB = AL(OFF_T + (size_t)N * 128 * 2);         // N*128 bf16 (x cast)

// ---------- weight cast into fragment-major layout + ws zeroing ----------
// frag index: off = ((nt*KB + kb)*64 + lane)*8 + j ; n = nt*16 + (lane&15),
// k = kb*32 + (lane>>4)*8 + j.  Source W is [k][n] row-major.
__global__ void prep_w(const float* __restrict__ WQ, const float* __restrict__ WK,
                       const float* __restrict__ WV, const float* __restrict__ WO,
                       const float* __restrict__ W1, const float* __restrict__ W2,
                       unsigned short* __restrict__ WQKVp, unsigned short* __restrict__ WOp,
                       float* __restrict__ W1pf, unsigned short* __restrict__ W2p,
                       unsigned* __restrict__ zbase) {
    if (blockIdx.x >= 512) {  // zero counts/cursors/banks/done
        size_t i = (size_t)(blockIdx.x - 512) * 256 + threadIdx.x;
        if (i < ZW) zbase[i] = 0u;
        return;
    }
    int gid = blockIdx.x * 256 + threadIdx.x;  // 131072 total
    if (gid < 49152) {                         // QKV: NT=8, KB=4 per slice
        int s = gid >> 14, r = gid & 16383;
        int nt = r >> 11, kb = (r >> 9) & 3, lane = (r >> 3) & 63, j = r & 7;
        int n = nt * 16 + (lane & 15);
        int k = kb * 32 + (lane >> 4) * 8 + j;
        const float* W = (s == 0) ? WQ : (s == 1) ? WK : WV;
        WQKVp[gid] = f2b(W[k * 128 + n]);
    } else if (gid < 65536) {  // WO: NT=8, KB=4
        int r = gid - 49152;
        int nt = r >> 11, kb = (r >> 9) & 3, lane = (r >> 3) & 63, j = r & 7;
        int n = nt * 16 + (lane & 15);
        int k = kb * 32 + (lane >> 4) * 8 + j;
        WOp[r] = f2b(WO[k * 128 + n]);
    } else if (gid < 98304) {  // W1: NT=16, KB=4 (src [128][256])
        int r = gid - 65536;
        int nt = r >> 11, kb = (r >> 9) & 3, lane = (r >> 3) & 63, j = r & 7;
        int n = nt * 16 + (lane & 15);
        int k = kb * 32 + (lane >> 4) * 8 + j;
        W1pf[r] = W1[k * 256 + n];
    } else {  // W2: NT=8, KB=8 (src [256][128])
        int r = gid - 98304;
        int nt = r >> 12, kb = (r >> 9) & 7, lane = (r >> 3) & 63, j = r & 7;
        int n = nt * 16 + (lane & 15);
        int k = kb * 32 + (lane >> 4) * 8 + j;
        W2p[r] = f2b(W2[k * 128 + n]);
    }
}

// ---------- CSR build ----------
__global__ void hist_k(const int* __restrict__ eidx, int* __restrict__ counts) {
    int e = blockIdx.x * 256 + threadIdx.x;
    if (e < E) atomicAdd(&counts[eidx[E + e]], 1);
}

// block-local exclusive scan; last finishing block scans the block sums
__global__ void scan_a(const int* __restrict__ counts, int* __restrict__ offs,
                       int* __restrict__ bsum, int* __restrict__ bpref,
                       int* __restrict__ done) {
    __shared__ int sm[256];
    __shared__ int ticket;
    int t = threadIdx.x;
    int gi = blockIdx.x * 256 + t;
    int v = (gi < N) ? counts[gi] : 0;
    sm[t] = v;
    __syncthreads();
    for (int o = 1; o < 256; o <<= 1) {
        int x = (t >= o) ? sm[t - o] : 0;
        __syncthreads();
        sm[t] += x;
        __syncthreads();
    }
    if (gi < N) offs[gi] = sm[t] - v;
    if (t == 255) bsum[blockIdx.x] = sm[255];
    __threadfence();
    if (t == 0) ticket = atomicAdd(done, 1);
    __syncthreads();
    if (ticket == (int)gridDim.x - 1) {
        int bv = (t < (int)gridDim.x) ? atomicAdd(&bsum[t], 0) : 0;  // coherent read
        sm[t] = bv;
        __syncthreads();
        for (int o = 1; o < 256; o <<= 1) {
            int x = (t >= o) ? sm[t - o] : 0;
            __syncthreads();
            sm[t] += x;
            __syncthreads();
        }
        bpref[t] = sm[t] - bv;
    }
}

__global__ void fill_k(const int* __restrict__ eidx, const int* __restrict__ offs,
                       const int* __restrict__ bpref,
                       int* __restrict__ cursors, int* __restrict__ csr) {
    int e = blockIdx.x * 256 + threadIdx.x;
    if (e < E) {
        int d = eidx[E + e];
        int p = atomicAdd(&cursors[d], 1);
        csr[offs[d] + bpref[d >> 8] + p] = eidx[e];
    }
}

// ---------- QKV: 64-row tiles; Q pre-scaled, K|V interleaved; x bf16 copy ----------
__global__ __launch_bounds__(256) void qkv_k(const float* __restrict__ x,
                                             const unsigned short* __restrict__ WQKVp,
                                             unsigned short* __restrict__ q,
                                             unsigned short* __restrict__ kv,
                                             unsigned short* __restrict__ xb) {
    __shared__ unsigned short As[64][136];
    __shared__ unsigned short Cs[64][136];
    const int tid = threadIdx.x;
    const int lane = tid & 63, wave = tid >> 6;
    const int quad = lane >> 4, l15 = lane & 15;
    const int wr = wave >> 1, wc = wave & 1;
    const int row0 = blockIdx.x * 64;

#pragma unroll
    for (int it = 0; it < 4; it++) {
        int c = tid + it * 256;
        int r = c >> 4, k8 = (c & 15) * 8;
        int grow = row0 + r;
        uint4 val = {0u, 0u, 0u, 0u};
        if (grow < N) {
            const float* ap = x + (size_t)grow * 128 + k8;
            float4 f0 = *(const float4*)ap;
            float4 f1 = *(const float4*)(ap + 4);
            val.x = pack2(f0.x, f0.y);
            val.y = pack2(f0.z, f0.w);
            val.z = pack2(f1.x, f1.y);
            val.w = pack2(f1.z, f1.w);
        }
        *(uint4*)&As[r][k8] = val;
    }
    __syncthreads();

    // write bf16 x copy for wo_k's residual (coalesced)
#pragma unroll
    for (int j = 0; j < 4; j++) {
        int idx = tid + j * 256;
        int u = idx >> 4, col8 = (idx & 15) * 8;
        int grow = row0 + u;
        if (grow < N) *(uint4*)(xb + (size_t)grow * 128 + col8) = *(const uint4*)&As[u][col8];
    }

    for (int s = 0; s < 3; s++) {
        f32x4 acc[2][4];
#pragma unroll
        for (int i = 0; i < 2; i++)
#pragma unroll
            for (int j = 0; j < 4; j++) acc[i][j] = (f32x4){0.f, 0.f, 0.f, 0.f};
#pragma unroll
        for (int ks = 0; ks < 4; ks++) {
            int k0 = ks * 32 + quad * 8;
            bfrag8 a0 = *(const bfrag8*)&As[wr * 32 + l15][k0];
            bfrag8 a1 = *(const bfrag8*)&As[wr * 32 + 16 + l15][k0];
#pragma unroll
            for (int jn = 0; jn < 4; jn++) {
                int nt = wc * 4 + jn;
                bfrag8 b = *(const bfrag8*)(WQKVp + ((((size_t)s * 8 + nt) * 4 + ks) * 64 + lane) * 8);
                acc[0][jn] = __builtin_amdgcn_mfma_f32_16x16x32_bf16(a0, b, acc[0][jn], 0, 0, 0);
                acc[1][jn] = __builtin_amdgcn_mfma_f32_16x16x32_bf16(a1, b, acc[1][jn], 0, 0, 0);
            }
        }
        if (s) __syncthreads();  // prior slice store-out done
        float sc = (s == 0) ? QSCALE : 1.0f;
#pragma unroll
        for (int i = 0; i < 2; i++) {
            int rb = wr * 32 + i * 16 + quad * 4;
#pragma unroll
            for (int jn = 0; jn < 4; jn++) {
                int cl = wc * 64 + jn * 16 + l15;
#pragma unroll
                for (int r = 0; r < 4; r++) Cs[rb + r][cl] = f2b(acc[i][jn][r] * sc);
            }
        }
        __syncthreads();
#pragma unroll
        for (int j = 0; j < 4; j++) {
            int idx = tid + j * 256;
            int u = idx >> 4, col8 = (idx & 15) * 8;
            int grow = row0 + u;
            if (grow < N) {
                uint4 v = *(const uint4*)&Cs[u][col8];
                if (s == 0)
                    *(uint4*)(q + (size_t)grow * 128 + col8) = v;
                else
                    *(uint4*)(kv + (size_t)grow * 256 + (s == 2 ? 128 : 0) + col8) = v;
            }
        }
    }
}

// ---------- attention: one wave per destination node; unroll 8/4/1 ----------
__global__ __launch_bounds__(256) void attn_k(const unsigned short* __restrict__ qb,
                                              const unsigned short* __restrict__ kv,
                                              const int* __restrict__ csr,
                                              const int* __restrict__ offs,
                                              const int* __restrict__ bpref,
                                              const int* __restrict__ counts,
                                              unsigned short* __restrict__ agg) {
    const int wave = threadIdx.x >> 6;
    const int i = blockIdx.x * 4 + wave;
    if (i >= N) return;
    const int lane = threadIdx.x & 63;
    const unsigned short* kvl = kv + (size_t)lane * 2;
    float2 q = ld2b(qb + (size_t)i * 128 + lane * 2);  // pre-scaled by QSCALE
    int off = offs[i] + bpref[i >> 8];
    int deg = counts[i];
    float s = 0.f, ax = 0.f, ay = 0.f;
    for (int base = 0; base < deg; base += 64) {
        int rem = deg - base;
        if (rem > 64) rem = 64;
        int myj = (lane < rem) ? csr[off + base + lane] : 0;
        int e = 0;
        for (; e + 8 <= rem; e += 8) {
            const unsigned short* r0 = kvl + (size_t)__shfl(myj, e + 0, 64) * 256;
            const unsigned short* r1 = kvl + (size_t)__shfl(myj, e + 1, 64) * 256;
            const unsigned short* r2 = kvl + (size_t)__shfl(myj, e + 2, 64) * 256;
            const unsigned short* r3 = kvl + (size_t)__shfl(myj, e + 3, 64) * 256;
            const unsigned short* r4 = kvl + (size_t)__shfl(myj, e + 4, 64) * 256;
            const unsigned short* r5 = kvl + (size_t)__shfl(myj, e + 5, 64) * 256;
            const unsigned short* r6 = kvl + (size_t)__shfl(myj, e + 6, 64) * 256;
            const unsigned short* r7 = kvl + (size_t)__shfl(myj, e + 7, 64) * 256;
            float2 k0 = ld2b(r0), v0 = ld2b(r0 + 128);
            float2 k1 = ld2b(r1), v1 = ld2b(r1 + 128);
            float2 k2 = ld2b(r2), v2 = ld2b(r2 + 128);
            float2 k3 = ld2b(r3), v3 = ld2b(r3 + 128);
            float2 k4 = ld2b(r4), v4 = ld2b(r4 + 128);
            float2 k5 = ld2b(r5), v5 = ld2b(r5 + 128);
            float2 k6 = ld2b(r6), v6 = ld2b(r6 + 128);
            float2 k7 = ld2b(r7), v7 = ld2b(r7 + 128);
            float p0 = q.x * k0.x + q.y * k0.y;
            float p1 = q.x * k1.x + q.y * k1.y;
            float p2 = q.x * k2.x + q.y * k2.y;
            float p3 = q.x * k3.x + q.y * k3.y;
            float p4 = q.x * k4.x + q.y * k4.y;
            float p5 = q.x * k5.x + q.y * k5.y;
            float p6 = q.x * k6.x + q.y * k6.y;
            float p7 = q.x * k7.x + q.y * k7.y;
            p0 += __shfl_xor(p0, 1, 64); p1 += __shfl_xor(p1, 1, 64);
            p2 += __shfl_xor(p2, 1, 64); p3 += __shfl_xor(p3, 1, 64);
            p4 += __shfl_xor(p4, 1, 64); p5 += __shfl_xor(p5, 1, 64);
            p6 += __shfl_xor(p6, 1, 64); p7 += __shfl_xor(p7, 1, 64);
            p0 += __shfl_xor(p0, 2, 64); p1 += __shfl_xor(p1, 2, 64);
            p2 += __shfl_xor(p2, 2, 64); p3 += __shfl_xor(p3, 2, 64);
            p4 += __shfl_xor(p4, 2, 64); p5 += __shfl_xor(p5, 2, 64);
            p6 += __shfl_xor(p6, 2, 64); p7 += __shfl_xor(p7, 2, 64);
            p0 += __shfl_xor(p0, 4, 64); p1 += __shfl_xor(p1, 4, 64);
            p2 += __shfl_xor(p2, 4, 64); p3 += __shfl_xor(p3, 4, 64);
            p4 += __shfl_xor(p4, 4, 64); p5 += __shfl_xor(p5, 4, 64);
            p6 += __shfl_xor(p6, 4, 64); p7 += __shfl_xor(p7, 4, 64);
            float w0 = exp2f(fminf(fmaxf(p0, -CLIP2), CLIP2));
            float w1 = exp2f(fminf(fmaxf(p1, -CLIP2), CLIP2));
            float w2 = exp2f(fminf(fmaxf(p2, -CLIP2), CLIP2));
            float w3 = exp2f(fminf(fmaxf(p3, -CLIP2), CLIP2));
            float w4 = exp2f(fminf(fmaxf(p4, -CLIP2), CLIP2));
            float w5 = exp2f(fminf(fmaxf(p5, -CLIP2), CLIP2));
            float w6 = exp2f(fminf(fmaxf(p6, -CLIP2), CLIP2));
            float w7 = exp2f(fminf(fmaxf(p7, -CLIP2), CLIP2));
            s += w0 + w1 + w2 + w3 + w4 + w5 + w6 + w7;
            ax += w0 * v0.x + w1 * v1.x + w2 * v2.x + w3 * v3.x;
            ax += w4 * v4.x + w5 * v5.x + w6 * v6.x + w7 * v7.x;
            ay += w0 * v0.y + w1 * v1.y + w2 * v2.y + w3 * v3.y;
            ay += w4 * v4.y + w5 * v5.y + w6 * v6.y + w7 * v7.y;
        }
        if (e + 4 <= rem) {
            const unsigned short* r0 = kvl + (size_t)__shfl(myj, e + 0, 64) * 256;
            const unsigned short* r1 = kvl + (size_t)__shfl(myj, e + 1, 64) * 256;
            const unsigned short* r2 = kvl + (size_t)__shfl(myj, e + 2, 64) * 256;
            const unsigned short* r3 = kvl + (size_t)__shfl(myj, e + 3, 64) * 256;
            float2 k0 = ld2b(r0), v0 = ld2b(r0 + 128);
            float2 k1 = ld2b(r1), v1 = ld2b(r1 + 128);
            float2 k2 = ld2b(r2), v2 = ld2b(r2 + 128);
            float2 k3 = ld2b(r3), v3 = ld2b(r3 + 128);
            float p0 = q.x * k0.x + q.y * k0.y;
            float p1 = q.x * k1.x + q.y * k1.y;
            float p2 = q.x * k2.x + q.y * k2.y;
            float p3 = q.x * k3.x + q.y * k3.y;
            p0 += __shfl_xor(p0, 1, 64); p1 += __shfl_xor(p1, 1, 64);
            p2 += __shfl_xor(p2, 1, 64); p3 += __shfl_xor(p3, 1, 64);
            p0 += __shfl_xor(p0, 2, 64); p1 += __shfl_xor(p1, 2, 64);
            p2 += __shfl_xor(p2, 2, 64); p3 += __shfl_xor(p3, 2, 64);
            p0 += __shfl_xor(p0, 4, 64); p1 += __shfl_xor(p1, 4, 64);
            p2 += __shfl_xor(p2, 4, 64); p3 += __shfl_xor(p3, 4, 64);
            float w0 = exp2f(fminf(fmaxf(p0, -CLIP2), CLIP2));
            float w1 = exp2f(fminf(fmaxf(p1, -CLIP2), CLIP2));
            float w2 = exp2f(fminf(fmaxf(p2, -CLIP2), CLIP2));
            float w3 = exp2f(fminf(fmaxf(p3, -CLIP2), CLIP2));
            s += w0 + w1 + w2 + w3;
            ax += w0 * v0.x + w1 * v1.x + w2 * v2.x + w3 * v3.x;
            ay += w0 * v0.y + w1 * v1.y + w2 * v2.y + w3 * v3.y;
            e += 4;
        }
        for (; e < rem; e++) {
            const unsigned short* r = kvl + (size_t)__shfl(myj, e, 64) * 256;
            float2 k = ld2b(r), v = ld2b(r + 128);
            float p = q.x * k.x + q.y * k.y;
            p += __shfl_xor(p, 1, 64);
            p += __shfl_xor(p, 2, 64);
            p += __shfl_xor(p, 4, 64);
            float w = exp2f(fminf(fmaxf(p, -CLIP2), CLIP2));
            s += w;
            ax += w * v.x;
            ay += w * v.y;
        }
    }
    float inv = 1.0f / (s + 1e-16f);
    unsigned o = pack2(ax * inv, ay * inv);
    *(unsigned*)(agg + (size_t)i * 128 + lane * 2) = o;
}

// ---------- WO projection + residual + BN1 stats (banked), 64-row ----------
__global__ __launch_bounds__(256) void wo_k(const unsigned short* __restrict__ agg,
                                            const unsigned short* __restrict__ WOp,
                                            const unsigned short* __restrict__ xb,
                                            const float* __restrict__ bO,
                                            unsigned short* __restrict__ Yb,
                                            float* __restrict__ bank1) {
    __shared__ unsigned short As[64][136];  // agg tile; reused as C bounce
    __shared__ unsigned short Xb[64][136];  // x residual (bf16)
    __shared__ float Cf[256];
    const int tid = threadIdx.x;
    const int lane = tid & 63, wave = tid >> 6;
    const int quad = lane >> 4, l15 = lane & 15;
    const int wr = wave >> 1, wc = wave & 1;
    const int row0 = blockIdx.x * 64;

    Cf[tid] = 0.f;
#pragma unroll
    for (int it = 0; it < 4; it++) {
        int c = tid + it * 256;
        int r = c >> 4, k8 = (c & 15) * 8;
        int grow = row0 + r;
        uint4 val = {0u, 0u, 0u, 0u};
        uint4 xv = {0u, 0u, 0u, 0u};
        if (grow < N) {
            val = *(const uint4*)(agg + (size_t)grow * 128 + k8);
            xv = *(const uint4*)(xb + (size_t)grow * 128 + k8);
        }
        *(uint4*)&As[r][k8] = val;
        *(uint4*)&Xb[r][k8] = xv;
    }
    __syncthreads();

    f32x4 acc[2][4];
#pragma unroll
    for (int i = 0; i < 2; i++)
#pragma unroll
        for (int j = 0; j < 4; j++) acc[i][j] = (f32x4){0.f, 0.f, 0.f, 0.f};
#pragma unroll
    for (int ks = 0; ks < 4; ks++) {
        int k0 = ks * 32 + quad * 8;
        bfrag8 a0 = *(const bfrag8*)&As[wr * 32 + l15][k0];
        bfrag8 a1 = *(const bfrag8*)&As[wr * 32 + 16 + l15][k0];
#pragma unroll
        for (int jn = 0; jn < 4; jn++) {
            int nt = wc * 4 + jn;
            bfrag8 b = *(const bfrag8*)(WOp + (((size_t)nt * 4 + ks) * 64 + lane) * 8);
            acc[0][jn] = __builtin_amdgcn_mfma_f32_16x16x32_bf16(a0, b, acc[0][jn], 0, 0, 0);
            acc[1][jn] = __builtin_amdgcn_mfma_f32_16x16x32_bf16(a1, b, acc[1][jn], 0, 0, 0);
        }
    }
    __syncthreads();  // all As reads done -> reuse as C bounce

    unsigned short(*Cs)[136] = As;
    float colS[4] = {0.f, 0.f, 0.f, 0.f}, colQ[4] = {0.f, 0.f, 0.f, 0.f};
#pragma unroll
    for (int i = 0; i < 2; i++) {
        int rb = wr * 32 + i * 16 + quad * 4;
#pragma unroll
        for (int jn = 0; jn < 4; jn++) {
            int cl = wc * 64 + jn * 16 + l15;
            float bv = bO[cl];
#pragma unroll
            for (int r = 0; r < 4; r++) {
                int rl = rb + r;
                float v = acc[i][jn][r] + bv + b2f(Xb[rl][cl]);
                Cs[rl][cl] = f2b(v);
                if (row0 + rl < N) {
                    colS[jn] += v;
                    colQ[jn] += v * v;
                }
            }
        }
    }
#pragma unroll
    for (int jn = 0; jn < 4; jn++) {
        float s = colS[jn], q = colQ[jn];
        s += __shfl_xor(s, 16, 64);
        q += __shfl_xor(q, 16, 64);
        s += __shfl_xor(s, 32, 64);
        q += __shfl_xor(q, 32, 64);
        if (quad == 0) {
            int cl = wc * 64 + jn * 16 + l15;
            atomicAdd(&Cf[cl], s);
            atomicAdd(&Cf[128 + cl], q);
        }
    }
    __syncthreads();
    atomicAdd(&bank1[(size_t)(blockIdx.x & (NBANK - 1)) * 256 + tid], Cf[tid]);
#pragma unroll
    for (int j = 0; j < 4; j++) {
        int idx = tid + j * 256;
        int u = idx >> 4, col8 = (idx & 15) * 8;
        int grow = row0 + u;
        if (grow < N) *(uint4*)(Yb + (size_t)grow * 128 + col8) = *(const uint4*)&Cs[u][col8];
    }
}

// ---------- BN1 finalize + W1 scale + folded FFN bias, one kernel ----------
__global__ __launch_bounds__(256) void bnscale_k(const float* __restrict__ bank1,
                                                 const float* __restrict__ g, const float* __restrict__ be,
                                                 const float* __restrict__ W1, const float* __restrict__ b1,
                                                 const float* __restrict__ W1pf,
                                                 float* __restrict__ ss, float* __restrict__ b1p,
                                                 unsigned short* __restrict__ W1p) {
    __shared__ float sm[256];
    __shared__ float scl[128];
    __shared__ float shf[128];
    int t = threadIdx.x;
    float s = 0.f;
    for (int cp = 0; cp < NBANK; cp++) s += bank1[cp * 256 + t];
    sm[t] = s;
    __syncthreads();
    if (t < 128) {
        float mu = sm[t] * (1.f / N);
        float var = sm[128 + t] * (1.f / N) - mu * mu;
        float sc = g[t] * rsqrtf(var + 1e-5f);
        float sh = be[t] - mu * sc;
        scl[t] = sc;
        shf[t] = sh;
        if (blockIdx.x == 0) {
            ss[t] = sc;
            ss[128 + t] = sh;
        }
    }
    __syncthreads();
    int i = blockIdx.x * 256 + t;  // 128 blocks * 256 = 32768
    int k = ((i >> 9) & 3) * 32 + (((i >> 3) & 63) >> 4) * 8 + (i & 7);
    W1p[i] = f2b(W1pf[i] * scl[k]);
    if (blockIdx.x == 0) {
        float acc = b1[t];
#pragma unroll 4
        for (int kk = 0; kk < 128; kk++) acc += shf[kk] * W1[kk * 256 + t];
        b1p[t] = acc;
    }
}

// ---------- fused FFN, 64-row; Z in LDS; banked BN2 stats ----------
__global__ __launch_bounds__(256) void ffn_k(const unsigned short* __restrict__ Yb,
                                             const unsigned short* __restrict__ W1p,
                                             const unsigned short* __restrict__ W2p,
                                             const float* __restrict__ ss1,
                                             const float* __restrict__ b1p,
                                             const float* __restrict__ b2,
                                             unsigned short* __restrict__ Tb,
                                             float* __restrict__ bank2) {
    __shared__ unsigned short As[64][136];  // Y tile, kept for residual
    __shared__ unsigned short Zs[64][264];  // Z tile; reused as T bounce
    __shared__ float Cf[640];               // ss1(256) | b1p(256) | b2(128)
    const int tid = threadIdx.x;
    const int lane = tid & 63, wave = tid >> 6;
    const int quad = lane >> 4, l15 = lane & 15;
    const int wr = wave >> 1, wc = wave & 1;
    const int row0 = blockIdx.x * 64;

    Cf[tid] = ss1[tid];
    Cf[256 + tid] = b1p[tid];
    if (tid < 128) Cf[512 + tid] = b2[tid];
#pragma unroll
    for (int it = 0; it < 4; it++) {
        int c = tid + it * 256;
        int r = c >> 4, k8 = (c & 15) * 8;
        int grow = row0 + r;
        uint4 val = {0u, 0u, 0u, 0u};
        if (grow < N) val = *(const uint4*)(Yb + (size_t)grow * 128 + k8);
        *(uint4*)&As[r][k8] = val;
    }
    __syncthreads();

    // gemm1: Z = relu(Y @ W1' + b1')
#pragma unroll
    for (int h = 0; h < 2; h++) {
        f32x4 acc[2][4];
#pragma unroll
        for (int i = 0; i < 2; i++)
#pragma unroll
            for (int j = 0; j < 4; j++) acc[i][j] = (f32x4){0.f, 0.f, 0.f, 0.f};
#pragma unroll
        for (int ks = 0; ks < 4; ks++) {
            int k0 = ks * 32 + quad * 8;
            bfrag8 a0 = *(const bfrag8*)&As[wr * 32 + l15][k0];
            bfrag8 a1 = *(const bfrag8*)&As[wr * 32 + 16 + l15][k0];
#pragma unroll
            for (int jn = 0; jn < 4; jn++) {
                int nt = h * 8 + wc * 4 + jn;
                bfrag8 b = *(const bfrag8*)(W1p + (((size_t)nt * 4 + ks) * 64 + lane) * 8);
                acc[0][jn] = __builtin_amdgcn_mfma_f32_16x16x32_bf16(a0, b, acc[0][jn], 0, 0, 0);
                acc[1][jn] = __builtin_amdgcn_mfma_f32_16x16x32_bf16(a1, b, acc[1][jn], 0, 0, 0);
            }
        }
#pragma unroll
        for (int i = 0; i < 2; i++) {
            int rb = wr * 32 + i * 16 + quad * 4;
#pragma unroll
            for (int jn = 0; jn < 4; jn++) {
                int gc = h * 128 + wc * 64 + jn * 16 + l15;
                float bv = Cf[256 + gc];
#pragma unroll
                for (int r = 0; r < 4; r++)
                    Zs[rb + r][gc] = f2b(fmaxf(acc[i][jn][r] + bv, 0.f));
            }
        }
    }
    __syncthreads();  // Z complete

    // gemm2: T = Z @ W2 + b2 + BN1(Y)
    f32x4 acc2[2][4];
#pragma unroll
    for (int i = 0; i < 2; i++)
#pragma unroll
        for (int j = 0; j < 4; j++) acc2[i][j] = (f32x4){0.f, 0.f, 0.f, 0.f};
#pragma unroll
    for (int ks = 0; ks < 8; ks++) {
        int k0 = ks * 32 + quad * 8;
        bfrag8 a0 = *(const bfrag8*)&Zs[wr * 32 + l15][k0];
        bfrag8 a1 = *(const bfrag8*)&Zs[wr * 32 + 16 + l15][k0];
#pragma unroll
        for (int jn = 0; jn < 4; jn++) {
            int nt = wc * 4 + jn;
            bfrag8 b = *(const bfrag8*)(W2p + (((size_t)nt * 8 + ks) * 64 + lane) * 8);
            acc2[0][jn] = __builtin_amdgcn_mfma_f32_16x16x32_bf16(a0, b, acc2[0][jn], 0, 0, 0);
            acc2[1][jn] = __builtin_amdgcn_mfma_f32_16x16x32_bf16(a1, b, acc2[1][jn], 0, 0, 0);
        }
    }
    __syncthreads();  // Zs reads done -> reuse as T bounce

    unsigned short(*Ts)[136] = (unsigned short(*)[136]) & Zs[0][0];
    float colS[4] = {0.f, 0.f, 0.f, 0.f}, colQ[4] = {0.f, 0.f, 0.f, 0.f};
#pragma unroll
    for (int i = 0; i < 2; i++) {
        int rb = wr * 32 + i * 16 + quad * 4;
#pragma unroll
        for (int jn = 0; jn < 4; jn++) {
            int cl = wc * 64 + jn * 16 + l15;
            float s1v = Cf[cl], sh1v = Cf[128 + cl], b2v = Cf[512 + cl];
#pragma unroll
            for (int r = 0; r < 4; r++) {
                int rl = rb + r;
                float yv = b2f(As[rl][cl]);
                float v = acc2[i][jn][r] + b2v + yv * s1v + sh1v;
                Ts[rl][cl] = f2b(v);
                if (row0 + rl < N) {
                    colS[jn] += v;
                    colQ[jn] += v * v;
                }
            }
        }
    }
    __syncthreads();  // Ts writes + all Cf reads done
    Cf[tid] = 0.f;
    __syncthreads();
#pragma unroll
    for (int jn = 0; jn < 4; jn++) {
        float s = colS[jn], q = colQ[jn];
        s += __shfl_xor(s, 16, 64);
        q += __shfl_xor(q, 16, 64);
        s += __shfl_xor(s, 32, 64);
        q += __shfl_xor(q, 32, 64);
        if (quad == 0) {
            int cl = wc * 64 + jn * 16 + l15;
            atomicAdd(&Cf[cl], s);
            atomicAdd(&Cf[128 + cl], q);
        }
    }
    __syncthreads();
    atomicAdd(&bank2[(size_t)(blockIdx.x & (NBANK - 1)) * 256 + tid], Cf[tid]);
#pragma unroll
    for (int j = 0; j < 4; j++) {
        int idx = tid + j * 256;
        int u = idx >> 4, col8 = (idx & 15) * 8;
        int grow = row0 + u;
        if (grow < N) *(uint4*)(Tb + (size_t)grow * 128 + col8) = *(const uint4*)&Ts[u][col8];
    }
}

__global__ void bnfin2_k(const float* __restrict__ bank2,
                         const float* __restrict__ g, const float* __restrict__ be,
                         float* __restrict__ ss) {
    __shared__ float sm[256];
    int t = threadIdx.x;
    float s = 0.f;
    for (int cp = 0; cp < NBANK; cp++) s += bank2[cp * 256 + t];
    sm[t] = s;
    __syncthreads();
    if (t < 128) {
        float mu = sm[t] * (1.f / N);
        float var = sm[128 + t] * (1.f / N) - mu * mu;
        float sc = g[t] * rsqrtf(var + 1e-5f);
        ss[t] = sc;
        ss[128 + t] = be[t] - mu * sc;
    }
}

__global__ void bnout_k(const unsigned short* __restrict__ T, const float* __restrict__ ss,
                        float* __restrict__ Out) {
    size_t idx = ((size_t)blockIdx.x * 256 + threadIdx.x) * 8;
    if (idx >= (size_t)N * 128) return;
    int c0 = (int)(idx & 127);
    uint4 tv = *(const uint4*)(T + idx);
    float f[8];
    f[0] = __uint_as_float(tv.x << 16);
    f[1] = __uint_as_float(tv.x & 0xFFFF0000u);
    f[2] = __uint_as_float(tv.y << 16);
    f[3] = __uint_as_float(tv.y & 0xFFFF0000u);
    f[4] = __uint_as_float(tv.z << 16);
    f[5] = __uint_as_float(tv.z & 0xFFFF0000u);
    f[6] = __uint_as_float(tv.w << 16);
    f[7] = __uint_as_float(tv.w & 0xFFFF0000u);
    float4 o0, o1;
    o0.x = f[0] * ss[c0 + 0] + ss[128 + c0 + 0];
    o0.y = f[1] * ss[c0 + 1] + ss[128 + c0 + 1];
    o0.z = f[2] * ss[c0 + 2] + ss[128 + c0 + 2];
    o0.w = f[3] * ss[c0 + 3] + ss[128 + c0 + 3];
    o1.x = f[4] * ss[c0 + 4] + ss[128 + c0 + 4];
    o1.y = f[5] * ss[c0 + 5] + ss[128 + c0 + 5];
    o1.z = f[6] * ss[c0 + 6] + ss[128 + c0 + 6];
    o1.w = f[7] * ss[c0 + 7] + ss[128 + c0 + 7];
    *(float4*)(Out + idx) = o0;
    *(float4*)(Out + idx + 4) = o1;
}

extern "C" void kernel_launch(void* const* d_in, const int* in_sizes, int n_in,
                              void* d_out, int out_size, void* d_ws, size_t ws_size,
                              hipStream_t stream) {
    const float* x = (const float*)d_in[0];
    const int* eidx = (const int*)d_in[1];
    const float* WQ = (const float*)d_in[2];
    const float* WK = (const float*)d_in[3];
    const float* WV = (const float*)d_in[4];
    const float* WO = (const float*)d_in[5];
    const float* bO = (const float*)d_in[6];
    const float* W1 = (const float*)d_in[7];
    const float* b1 = (const float*)d_in[8];
    const float* W2 = (const float*)d_in[9];
    const float* b2 = (const float*)d_in[10];
    const float* g1 = (const float*)d_in[11];
    const float* be1 = (const float*)d_in[12];
    const float* g2 = (const float*)d_in[13];
    const float* be2 = (const float*)d_in[14];
    float* out = (float*)d_out;

    char* ws = (char*)d_ws;
    int* counts = (int*)(ws + OFF_COUNTS);
    int* cursors = (int*)(ws + OFF_CURSORS);
    float* bank1 = (float*)(ws + OFF_BANK1);
    float* bank2 = (float*)(ws + OFF_BANK2);
    int* done = (int*)(ws + OFF_DONE);
    int* offs = (int*)(ws + OFF_OFFS);
    int* bsum = (int*)(ws + OFF_BSUM);
    int* bpref = (int*)(ws + OFF_BPREF);
    float* ss1 = (float*)(ws + OFF_SS1);
    float* ss2 = (float*)(ws + OFF_SS2);
    float* b1p = (float*)(ws + OFF_B1P);
    int* csr = (int*)(ws + OFF_CSR);
    unsigned short* WQKVp = (unsigned short*)(ws + OFF_WQKVP);
    unsigned short* WOp = (unsigned short*)(ws + OFF_WOP);
    float* W1pf = (float*)(ws + OFF_W1PF);
    unsigned short* W1p = (unsigned short*)(ws + OFF_W1P);
    unsigned short* W2p = (unsigned short*)(ws + OFF_W2P);
    unsigned short* qb = (unsigned short*)(ws + OFF_Q);
    unsigned short* kv = (unsigned short*)(ws + OFF_KV);
    unsigned short* agg = (unsigned short*)(ws + OFF_AGG);
    unsigned short* Yb = (unsigned short*)(ws + OFF_Y);
    unsigned short* Tb = (unsigned short*)(ws + OFF_T);
    unsigned short* xb = (unsigned short*)(ws + OFF_XB);

    const int ZB = (int)((ZW + 255) / 256);  // zeroing blocks
    prep_w<<<512 + ZB, 256, 0, stream>>>(WQ, WK, WV, WO, W1, W2, WQKVp, WOp, W1pf, W2p,
                                         (unsigned*)ws);

    const int EB = (E + 255) / 256;
    hist_k<<<EB, 256, 0, stream>>>(eidx, counts);
    scan_a<<<196, 256, 0, stream>>>(counts, offs, bsum, bpref, done);
    fill_k<<<EB, 256, 0, stream>>>(eidx, offs, bpref, cursors, csr);

    const int MB64 = (N + 63) / 64;  // 782
    qkv_k<<<MB64, 256, 0, stream>>>(x, WQKVp, qb, kv, xb);
    attn_k<<<(N + 3) / 4, 256, 0, stream>>>(qb, kv, csr, offs, bpref, counts, agg);
    wo_k<<<MB64, 256, 0, stream>>>(agg, WOp, xb, bO, Yb, bank1);
    bnscale_k<<<128, 256, 0, stream>>>(bank1, g1, be1, W1, b1, W1pf, ss1, b1p, W1p);
    ffn_k<<<MB64, 256, 0, stream>>>(Yb, W1p, W2p, ss1, b1p, b2, Tb, bank2);
    bnfin2_k<<<1, 256, 0, stream>>>(bank2, g2, be2, ss2);
    bnout_k<<<(int)(((size_t)N * 128 / 8 + 255) / 256), 256, 0, stream>>>(Tb, ss2, out);
}

// Round 8
// 264.868 us; speedup vs baseline: 1.0486x; 1.0486x over previous
//
#include <hip/hip_runtime.h>

#define DEV __device__ __forceinline__

constexpr int N = 50000;
constexpr int E = 500000;
constexpr int D = 128;
constexpr int DFF = 256;
constexpr int NBANK = 64;  // stats contention spread

typedef __attribute__((ext_vector_type(8))) short bfrag8;
typedef __attribute__((ext_vector_type(4))) float f32x4;

// ---------- helpers ----------
DEV unsigned short f2b(float f) {
    unsigned u = __float_as_uint(f);
    unsigned r = (u + 0x7FFFu + ((u >> 16) & 1u)) >> 16;
    return (unsigned short)r;
}
DEV unsigned pack2(float a, float b) {
    return (unsigned)f2b(a) | ((unsigned)f2b(b) << 16);
}
DEV float b2f(unsigned short v) { return __uint_as_float(((unsigned)v) << 16); }
DEV float lo16(unsigned u) { return __uint_as_float(u << 16); }
DEV float hi16(unsigned u) { return __uint_as_float(u & 0xFFFF0000u); }

// score = clip(dot/4, +-5); fold 0.25*log2e into Q, clip at 5*log2e, use exp2
constexpr float QSCALE = 0.36067376022224085f;  // 0.25 * log2(e)
constexpr float CLIP2 = 7.2134752044448170f;    // 5 * log2(e)

// ---------- workspace layout (bytes) ----------
constexpr size_t AL(size_t x) { return (x + 511) & ~(size_t)511; }
constexpr size_t OFF_COUNTS = 0;                                   // N int
constexpr size_t OFF_CURSORS = AL(OFF_COUNTS + (size_t)N * 4);     // N int
constexpr size_t OFF_BANK1 = AL(OFF_CURSORS + (size_t)N * 4);      // NBANK*256 f
constexpr size_t OFF_BANK2 = AL(OFF_BANK1 + NBANK * 256 * 4);      // NBANK*256 f
constexpr size_t OFF_DONE = OFF_BANK2 + NBANK * 256 * 4;           // 1 int (+pad)
constexpr size_t ZERO_END = OFF_DONE + 512;                        // zeroed by prep_w
constexpr size_t ZW = ZERO_END / 4;                                // words to zero
constexpr size_t OFF_OFFS = AL(ZERO_END);                          // N int
constexpr size_t OFF_BSUM = AL(OFF_OFFS + (size_t)N * 4);          // 256 int
constexpr size_t OFF_BPREF = AL(OFF_BSUM + 1024);                  // 256 int
constexpr size_t OFF_SS1 = AL(OFF_BPREF + 1024);                   // 256 f
constexpr size_t OFF_SS2 = AL(OFF_SS1 + 1024);                     // 256 f
constexpr size_t OFF_B1P = AL(OFF_SS2 + 1024);                     // 256 f
constexpr size_t OFF_CSR = AL(OFF_B1P + 1024);                     // E int
// weights in MFMA fragment-major order: frag[nt][kb][lane][8]
constexpr size_t OFF_WQKVP = AL(OFF_CSR + (size_t)E * 4);          // 3*16384 bf16
constexpr size_t OFF_WOP = AL(OFF_WQKVP + 49152 * 2);              // 16384 bf16
constexpr size_t OFF_W1PF = AL(OFF_WOP + 16384 * 2);               // 32768 f32 (pre-scale)
constexpr size_t OFF_W1P = AL(OFF_W1PF + 32768 * 4);               // 32768 bf16 (scaled)
constexpr size_t OFF_W2P = AL(OFF_W1P + 32768 * 2);                // 32768 bf16
constexpr size_t OFF_Q = AL(OFF_W2P + 32768 * 2);                  // N*128 bf16 (pre-scaled)
constexpr size_t OFF_KV = AL(OFF_Q + (size_t)N * 128 * 2);         // N*256 bf16, K|V interleaved
constexpr size_t OFF_AGG = AL(OFF_KV + (size_t)N * 256 * 2);       // N*128 bf16
constexpr size_t OFF_Y = AL(OFF_AGG + (size_t)N * 128 * 2);        // N*128 bf16
constexpr size_t OFF_T = AL(OFF_Y + (size_t)N * 128 * 2);          // N*128 bf16
constexpr size_t OFF_XB = AL(OFF_T + (size_t)N * 128 * 2);         // N*128 bf16 (x cast)

// ---------- weight cast into fragment-major layout + ws zeroing ----------
__global__ void prep_w(const float* __restrict__ WQ, const float* __restrict__ WK,
                       const float* __restrict__ WV, const float* __restrict__ WO,
                       const float* __restrict__ W1, const float* __restrict__ W2,
                       unsigned short* __restrict__ WQKVp, unsigned short* __restrict__ WOp,
                       float* __restrict__ W1pf, unsigned short* __restrict__ W2p,
                       unsigned* __restrict__ zbase) {
    if (blockIdx.x >= 512) {  // zero counts/cursors/banks/done
        size_t i = (size_t)(blockIdx.x - 512) * 256 + threadIdx.x;
        if (i < ZW) zbase[i] = 0u;
        return;
    }
    int gid = blockIdx.x * 256 + threadIdx.x;  // 131072 total
    if (gid < 49152) {                         // QKV: NT=8, KB=4 per slice
        int s = gid >> 14, r = gid & 16383;
        int nt = r >> 11, kb = (r >> 9) & 3, lane = (r >> 3) & 63, j = r & 7;
        int n = nt * 16 + (lane & 15);
        int k = kb * 32 + (lane >> 4) * 8 + j;
        const float* W = (s == 0) ? WQ : (s == 1) ? WK : WV;
        WQKVp[gid] = f2b(W[k * 128 + n]);
    } else if (gid < 65536) {  // WO: NT=8, KB=4
        int r = gid - 49152;
        int nt = r >> 11, kb = (r >> 9) & 3, lane = (r >> 3) & 63, j = r & 7;
        int n = nt * 16 + (lane & 15);
        int k = kb * 32 + (lane >> 4) * 8 + j;
        WOp[r] = f2b(WO[k * 128 + n]);
    } else if (gid < 98304) {  // W1: NT=16, KB=4 (src [128][256])
        int r = gid - 65536;
        int nt = r >> 11, kb = (r >> 9) & 3, lane = (r >> 3) & 63, j = r & 7;
        int n = nt * 16 + (lane & 15);
        int k = kb * 32 + (lane >> 4) * 8 + j;
        W1pf[r] = W1[k * 256 + n];
    } else {  // W2: NT=8, KB=8 (src [256][128])
        int r = gid - 98304;
        int nt = r >> 12, kb = (r >> 9) & 7, lane = (r >> 3) & 63, j = r & 7;
        int n = nt * 16 + (lane & 15);
        int k = kb * 32 + (lane >> 4) * 8 + j;
        W2p[r] = f2b(W2[k * 128 + n]);
    }
}

// ---------- CSR scan: block-local + last-block global ----------
__global__ void scan_a(const int* __restrict__ counts, int* __restrict__ offs,
                       int* __restrict__ bsum, int* __restrict__ bpref,
                       int* __restrict__ done) {
    __shared__ int sm[256];
    __shared__ int ticket;
    int t = threadIdx.x;
    int gi = blockIdx.x * 256 + t;
    int v = (gi < N) ? counts[gi] : 0;
    sm[t] = v;
    __syncthreads();
    for (int o = 1; o < 256; o <<= 1) {
        int x = (t >= o) ? sm[t - o] : 0;
        __syncthreads();
        sm[t] += x;
        __syncthreads();
    }
    if (gi < N) offs[gi] = sm[t] - v;
    if (t == 255) bsum[blockIdx.x] = sm[255];
    __threadfence();
    if (t == 0) ticket = atomicAdd(done, 1);
    __syncthreads();
    if (ticket == (int)gridDim.x - 1) {
        int bv = (t < (int)gridDim.x) ? atomicAdd(&bsum[t], 0) : 0;  // coherent read
        sm[t] = bv;
        __syncthreads();
        for (int o = 1; o < 256; o <<= 1) {
            int x = (t >= o) ? sm[t - o] : 0;
            __syncthreads();
            sm[t] += x;
            __syncthreads();
        }
        bpref[t] = sm[t] - bv;
    }
}

__global__ void fill_k(const int* __restrict__ eidx, const int* __restrict__ offs,
                       const int* __restrict__ bpref,
                       int* __restrict__ cursors, int* __restrict__ csr) {
    int e = blockIdx.x * 256 + threadIdx.x;
    if (e < E) {
        int d = eidx[E + e];
        int p = atomicAdd(&cursors[d], 1);
        csr[offs[d] + bpref[d >> 8] + p] = eidx[e];
    }
}

// ---------- QKV (64-row tiles) + histogram merged into one dispatch ----------
__global__ __launch_bounds__(256) void qkv_k(const float* __restrict__ x,
                                             const unsigned short* __restrict__ WQKVp,
                                             unsigned short* __restrict__ q,
                                             unsigned short* __restrict__ kv,
                                             unsigned short* __restrict__ xb,
                                             const int* __restrict__ eidx,
                                             int* __restrict__ counts, int nqkv) {
    if ((int)blockIdx.x >= nqkv) {  // histogram part (independent of qkv)
        int e = ((int)blockIdx.x - nqkv) * 256 + threadIdx.x;
        if (e < E) atomicAdd(&counts[eidx[E + e]], 1);
        return;
    }
    __shared__ unsigned short As[64][136];
    __shared__ unsigned short Cs[64][136];
    const int tid = threadIdx.x;
    const int lane = tid & 63, wave = tid >> 6;
    const int quad = lane >> 4, l15 = lane & 15;
    const int wr = wave >> 1, wc = wave & 1;
    const int row0 = blockIdx.x * 64;

#pragma unroll
    for (int it = 0; it < 4; it++) {
        int c = tid + it * 256;
        int r = c >> 4, k8 = (c & 15) * 8;
        int grow = row0 + r;
        uint4 val = {0u, 0u, 0u, 0u};
        if (grow < N) {
            const float* ap = x + (size_t)grow * 128 + k8;
            float4 f0 = *(const float4*)ap;
            float4 f1 = *(const float4*)(ap + 4);
            val.x = pack2(f0.x, f0.y);
            val.y = pack2(f0.z, f0.w);
            val.z = pack2(f1.x, f1.y);
            val.w = pack2(f1.z, f1.w);
        }
        *(uint4*)&As[r][k8] = val;
    }
    __syncthreads();

    // write bf16 x copy for wo_k's residual (coalesced)
#pragma unroll
    for (int j = 0; j < 4; j++) {
        int idx = tid + j * 256;
        int u = idx >> 4, col8 = (idx & 15) * 8;
        int grow = row0 + u;
        if (grow < N) *(uint4*)(xb + (size_t)grow * 128 + col8) = *(const uint4*)&As[u][col8];
    }

    for (int s = 0; s < 3; s++) {
        f32x4 acc[2][4];
#pragma unroll
        for (int i = 0; i < 2; i++)
#pragma unroll
            for (int j = 0; j < 4; j++) acc[i][j] = (f32x4){0.f, 0.f, 0.f, 0.f};
#pragma unroll
        for (int ks = 0; ks < 4; ks++) {
            int k0 = ks * 32 + quad * 8;
            bfrag8 a0 = *(const bfrag8*)&As[wr * 32 + l15][k0];
            bfrag8 a1 = *(const bfrag8*)&As[wr * 32 + 16 + l15][k0];
#pragma unroll
            for (int jn = 0; jn < 4; jn++) {
                int nt = wc * 4 + jn;
                bfrag8 b = *(const bfrag8*)(WQKVp + ((((size_t)s * 8 + nt) * 4 + ks) * 64 + lane) * 8);
                acc[0][jn] = __builtin_amdgcn_mfma_f32_16x16x32_bf16(a0, b, acc[0][jn], 0, 0, 0);
                acc[1][jn] = __builtin_amdgcn_mfma_f32_16x16x32_bf16(a1, b, acc[1][jn], 0, 0, 0);
            }
        }
        if (s) __syncthreads();  // prior slice store-out done
        float sc = (s == 0) ? QSCALE : 1.0f;
#pragma unroll
        for (int i = 0; i < 2; i++) {
            int rb = wr * 32 + i * 16 + quad * 4;
#pragma unroll
            for (int jn = 0; jn < 4; jn++) {
                int cl = wc * 64 + jn * 16 + l15;
#pragma unroll
                for (int r = 0; r < 4; r++) Cs[rb + r][cl] = f2b(acc[i][jn][r] * sc);
            }
        }
        __syncthreads();
#pragma unroll
        for (int j = 0; j < 4; j++) {
            int idx = tid + j * 256;
            int u = idx >> 4, col8 = (idx & 15) * 8;
            int grow = row0 + u;
            if (grow < N) {
                uint4 v = *(const uint4*)&Cs[u][col8];
                if (s == 0)
                    *(uint4*)(q + (size_t)grow * 128 + col8) = v;
                else
                    *(uint4*)(kv + (size_t)grow * 256 + (s == 2 ? 128 : 0) + col8) = v;
            }
        }
    }
}

// ---------- attention v2: lane = (edge-slot, half-head) ----------
// slot = lane>>4 (4 edges per group), m = lane&15 covers dims m*8..m*8+7.
// One uint4 gather per K/V half-row segment; 1 xor-shfl per edge for the dot;
// cross-slot reduction once per node.
__global__ __launch_bounds__(256) void attn_k(const unsigned short* __restrict__ qb,
                                              const unsigned short* __restrict__ kv,
                                              const int* __restrict__ csr,
                                              const int* __restrict__ offs,
                                              const int* __restrict__ bpref,
                                              const int* __restrict__ counts,
                                              unsigned short* __restrict__ agg) {
    const int wave = threadIdx.x >> 6;
    const int i = blockIdx.x * 4 + wave;
    if (i >= N) return;
    const int lane = threadIdx.x & 63;
    const int slot = lane >> 4;  // 0..3
    const int m = lane & 15;     // half-head index

    uint4 qv = *(const uint4*)(qb + (size_t)i * 128 + m * 8);  // pre-scaled
    const float q0 = lo16(qv.x), q1 = hi16(qv.x);
    const float q2 = lo16(qv.y), q3 = hi16(qv.y);
    const float q4 = lo16(qv.z), q5 = hi16(qv.z);
    const float q6 = lo16(qv.w), q7 = hi16(qv.w);

    int off = offs[i] + bpref[i >> 8];
    int deg = counts[i];
    const unsigned short* kvm = kv + m * 8;
    float s = 0.f;
    float a0 = 0.f, a1 = 0.f, a2 = 0.f, a3 = 0.f, a4 = 0.f, a5 = 0.f, a6 = 0.f, a7 = 0.f;

    for (int base = 0; base < deg; base += 64) {
        int rem = deg - base;
        if (rem > 64) rem = 64;
        int myj = (lane < rem) ? csr[off + base + lane] : 0;
        for (int e = 0; e < rem; e += 8) {
            int sA = e + slot;
            int jA = __shfl(myj, sA, 64);
            const unsigned short* pA = kvm + (size_t)jA * 256;
            uint4 kA = *(const uint4*)pA;
            uint4 vA = *(const uint4*)(pA + 128);
            bool two = (e + 4) < rem;
            float pdA = (q0 * lo16(kA.x) + q1 * hi16(kA.x)) + (q2 * lo16(kA.y) + q3 * hi16(kA.y)) +
                        (q4 * lo16(kA.z) + q5 * hi16(kA.z)) + (q6 * lo16(kA.w) + q7 * hi16(kA.w));
            pdA += __shfl_xor(pdA, 1, 64);
            float wA = exp2f(fminf(fmaxf(pdA, -CLIP2), CLIP2));
            wA = (sA < rem) ? wA : 0.f;
            if (two) {
                int sB = e + 4 + slot;
                int jB = __shfl(myj, sB, 64);
                const unsigned short* pB = kvm + (size_t)jB * 256;
                uint4 kB = *(const uint4*)pB;
                uint4 vB = *(const uint4*)(pB + 128);
                float pdB = (q0 * lo16(kB.x) + q1 * hi16(kB.x)) + (q2 * lo16(kB.y) + q3 * hi16(kB.y)) +
                            (q4 * lo16(kB.z) + q5 * hi16(kB.z)) + (q6 * lo16(kB.w) + q7 * hi16(kB.w));
                pdB += __shfl_xor(pdB, 1, 64);
                float wB = exp2f(fminf(fmaxf(pdB, -CLIP2), CLIP2));
                wB = (sB < rem) ? wB : 0.f;
                s += wA + wB;
                a0 += wA * lo16(vA.x) + wB * lo16(vB.x);
                a1 += wA * hi16(vA.x) + wB * hi16(vB.x);
                a2 += wA * lo16(vA.y) + wB * lo16(vB.y);
                a3 += wA * hi16(vA.y) + wB * hi16(vB.y);
                a4 += wA * lo16(vA.z) + wB * lo16(vB.z);
                a5 += wA * hi16(vA.z) + wB * hi16(vB.z);
                a6 += wA * lo16(vA.w) + wB * lo16(vB.w);
                a7 += wA * hi16(vA.w) + wB * hi16(vB.w);
            } else {
                s += wA;
                a0 += wA * lo16(vA.x);
                a1 += wA * hi16(vA.x);
                a2 += wA * lo16(vA.y);
                a3 += wA * hi16(vA.y);
                a4 += wA * lo16(vA.z);
                a5 += wA * hi16(vA.z);
                a6 += wA * lo16(vA.w);
                a7 += wA * hi16(vA.w);
            }
        }
    }
    // reduce across the 4 slots (lanes lane^16, lane^32)
#define SLOTRED(v)                 \
    v += __shfl_xor(v, 16, 64);    \
    v += __shfl_xor(v, 32, 64);
    SLOTRED(s)
    SLOTRED(a0) SLOTRED(a1) SLOTRED(a2) SLOTRED(a3)
    SLOTRED(a4) SLOTRED(a5) SLOTRED(a6) SLOTRED(a7)
#undef SLOTRED
    float inv = 1.0f / (s + 1e-16f);
    if (slot == 0) {
        uint4 o;
        o.x = pack2(a0 * inv, a1 * inv);
        o.y = pack2(a2 * inv, a3 * inv);
        o.z = pack2(a4 * inv, a5 * inv);
        o.w = pack2(a6 * inv, a7 * inv);
        *(uint4*)(agg + (size_t)i * 128 + m * 8) = o;
    }
}

// ---------- WO projection + residual + BN1 stats (banked), 64-row ----------
__global__ __launch_bounds__(256) void wo_k(const unsigned short* __restrict__ agg,
                                            const unsigned short* __restrict__ WOp,
                                            const unsigned short* __restrict__ xb,
                                            const float* __restrict__ bO,
                                            unsigned short* __restrict__ Yb,
                                            float* __restrict__ bank1) {
    __shared__ unsigned short As[64][136];  // agg tile; reused as C bounce
    __shared__ unsigned short Xb[64][136];  // x residual (bf16)
    __shared__ float Cf[256];
    const int tid = threadIdx.x;
    const int lane = tid & 63, wave = tid >> 6;
    const int quad = lane >> 4, l15 = lane & 15;
    const int wr = wave >> 1, wc = wave & 1;
    const int row0 = blockIdx.x * 64;

    Cf[tid] = 0.f;
#pragma unroll
    for (int it = 0; it < 4; it++) {
        int c = tid + it * 256;
        int r = c >> 4, k8 = (c & 15) * 8;
        int grow = row0 + r;
        uint4 val = {0u, 0u, 0u, 0u};
        uint4 xv = {0u, 0u, 0u, 0u};
        if (grow < N) {
            val = *(const uint4*)(agg + (size_t)grow * 128 + k8);
            xv = *(const uint4*)(xb + (size_t)grow * 128 + k8);
        }
        *(uint4*)&As[r][k8] = val;
        *(uint4*)&Xb[r][k8] = xv;
    }
    __syncthreads();

    f32x4 acc[2][4];
#pragma unroll
    for (int i = 0; i < 2; i++)
#pragma unroll
        for (int j = 0; j < 4; j++) acc[i][j] = (f32x4){0.f, 0.f, 0.f, 0.f};
#pragma unroll
    for (int ks = 0; ks < 4; ks++) {
        int k0 = ks * 32 + quad * 8;
        bfrag8 a0 = *(const bfrag8*)&As[wr * 32 + l15][k0];
        bfrag8 a1 = *(const bfrag8*)&As[wr * 32 + 16 + l15][k0];
#pragma unroll
        for (int jn = 0; jn < 4; jn++) {
            int nt = wc * 4 + jn;
            bfrag8 b = *(const bfrag8*)(WOp + (((size_t)nt * 4 + ks) * 64 + lane) * 8);
            acc[0][jn] = __builtin_amdgcn_mfma_f32_16x16x32_bf16(a0, b, acc[0][jn], 0, 0, 0);
            acc[1][jn] = __builtin_amdgcn_mfma_f32_16x16x32_bf16(a1, b, acc[1][jn], 0, 0, 0);
        }
    }
    __syncthreads();  // all As reads done -> reuse as C bounce

    unsigned short(*Cs)[136] = As;
    float colS[4] = {0.f, 0.f, 0.f, 0.f}, colQ[4] = {0.f, 0.f, 0.f, 0.f};
#pragma unroll
    for (int i = 0; i < 2; i++) {
        int rb = wr * 32 + i * 16 + quad * 4;
#pragma unroll
        for (int jn = 0; jn < 4; jn++) {
            int cl = wc * 64 + jn * 16 + l15;
            float bv = bO[cl];
#pragma unroll
            for (int r = 0; r < 4; r++) {
                int rl = rb + r;
                float v = acc[i][jn][r] + bv + b2f(Xb[rl][cl]);
                Cs[rl][cl] = f2b(v);
                if (row0 + rl < N) {
                    colS[jn] += v;
                    colQ[jn] += v * v;
                }
            }
        }
    }
#pragma unroll
    for (int jn = 0; jn < 4; jn++) {
        float s = colS[jn], q = colQ[jn];
        s += __shfl_xor(s, 16, 64);
        q += __shfl_xor(q, 16, 64);
        s += __shfl_xor(s, 32, 64);
        q += __shfl_xor(q, 32, 64);
        if (quad == 0) {
            int cl = wc * 64 + jn * 16 + l15;
            atomicAdd(&Cf[cl], s);
            atomicAdd(&Cf[128 + cl], q);
        }
    }
    __syncthreads();
    atomicAdd(&bank1[(size_t)(blockIdx.x & (NBANK - 1)) * 256 + tid], Cf[tid]);
#pragma unroll
    for (int j = 0; j < 4; j++) {
        int idx = tid + j * 256;
        int u = idx >> 4, col8 = (idx & 15) * 8;
        int grow = row0 + u;
        if (grow < N) *(uint4*)(Yb + (size_t)grow * 128 + col8) = *(const uint4*)&Cs[u][col8];
    }
}

// ---------- BN1 finalize + W1 scale + folded FFN bias, one kernel ----------
__global__ __launch_bounds__(256) void bnscale_k(const float* __restrict__ bank1,
                                                 const float* __restrict__ g, const float* __restrict__ be,
                                                 const float* __restrict__ W1, const float* __restrict__ b1,
                                                 const float* __restrict__ W1pf,
                                                 float* __restrict__ ss, float* __restrict__ b1p,
                                                 unsigned short* __restrict__ W1p) {
    __shared__ float sm[256];
    __shared__ float scl[128];
    __shared__ float shf[128];
    int t = threadIdx.x;
    float s = 0.f;
    for (int cp = 0; cp < NBANK; cp++) s += bank1[cp * 256 + t];
    sm[t] = s;
    __syncthreads();
    if (t < 128) {
        float mu = sm[t] * (1.f / N);
        float var = sm[128 + t] * (1.f / N) - mu * mu;
        float sc = g[t] * rsqrtf(var + 1e-5f);
        float sh = be[t] - mu * sc;
        scl[t] = sc;
        shf[t] = sh;
        if (blockIdx.x == 0) {
            ss[t] = sc;
            ss[128 + t] = sh;
        }
    }
    __syncthreads();
    int i = blockIdx.x * 256 + t;  // 128 blocks * 256 = 32768
    int k = ((i >> 9) & 3) * 32 + (((i >> 3) & 63) >> 4) * 8 + (i & 7);
    W1p[i] = f2b(W1pf[i] * scl[k]);
    if (blockIdx.x == 0) {
        float acc = b1[t];
#pragma unroll 4
        for (int kk = 0; kk < 128; kk++) acc += shf[kk] * W1[kk * 256 + t];
        b1p[t] = acc;
    }
}

// ---------- fused FFN, 64-row; Z in LDS; banked BN2 stats ----------
__global__ __launch_bounds__(256) void ffn_k(const unsigned short* __restrict__ Yb,
                                             const unsigned short* __restrict__ W1p,
                                             const unsigned short* __restrict__ W2p,
                                             const float* __restrict__ ss1,
                                             const float* __restrict__ b1p,
                                             const float* __restrict__ b2,
                                             unsigned short* __restrict__ Tb,
                                             float* __restrict__ bank2) {
    __shared__ unsigned short As[64][136];  // Y tile, kept for residual
    __shared__ unsigned short Zs[64][264];  // Z tile; reused as T bounce
    __shared__ float Cf[640];               // ss1(256) | b1p(256) | b2(128)
    const int tid = threadIdx.x;
    const int lane = tid & 63, wave = tid >> 6;
    const int quad = lane >> 4, l15 = lane & 15;
    const int wr = wave >> 1, wc = wave & 1;
    const int row0 = blockIdx.x * 64;

    Cf[tid] = ss1[tid];
    Cf[256 + tid] = b1p[tid];
    if (tid < 128) Cf[512 + tid] = b2[tid];
#pragma unroll
    for (int it = 0; it < 4; it++) {
        int c = tid + it * 256;
        int r = c >> 4, k8 = (c & 15) * 8;
        int grow = row0 + r;
        uint4 val = {0u, 0u, 0u, 0u};
        if (grow < N) val = *(const uint4*)(Yb + (size_t)grow * 128 + k8);
        *(uint4*)&As[r][k8] = val;
    }
    __syncthreads();

    // gemm1: Z = relu(Y @ W1' + b1')
#pragma unroll
    for (int h = 0; h < 2; h++) {
        f32x4 acc[2][4];
#pragma unroll
        for (int i = 0; i < 2; i++)
#pragma unroll
            for (int j = 0; j < 4; j++) acc[i][j] = (f32x4){0.f, 0.f, 0.f, 0.f};
#pragma unroll
        for (int ks = 0; ks < 4; ks++) {
            int k0 = ks * 32 + quad * 8;
            bfrag8 a0 = *(const bfrag8*)&As[wr * 32 + l15][k0];
            bfrag8 a1 = *(const bfrag8*)&As[wr * 32 + 16 + l15][k0];
#pragma unroll
            for (int jn = 0; jn < 4; jn++) {
                int nt = h * 8 + wc * 4 + jn;
                bfrag8 b = *(const bfrag8*)(W1p + (((size_t)nt * 4 + ks) * 64 + lane) * 8);
                acc[0][jn] = __builtin_amdgcn_mfma_f32_16x16x32_bf16(a0, b, acc[0][jn], 0, 0, 0);
                acc[1][jn] = __builtin_amdgcn_mfma_f32_16x16x32_bf16(a1, b, acc[1][jn], 0, 0, 0);
            }
        }
#pragma unroll
        for (int i = 0; i < 2; i++) {
            int rb = wr * 32 + i * 16 + quad * 4;
#pragma unroll
            for (int jn = 0; jn < 4; jn++) {
                int gc = h * 128 + wc * 64 + jn * 16 + l15;
                float bv = Cf[256 + gc];
#pragma unroll
                for (int r = 0; r < 4; r++)
                    Zs[rb + r][gc] = f2b(fmaxf(acc[i][jn][r] + bv, 0.f));
            }
        }
    }
    __syncthreads();  // Z complete

    // gemm2: T = Z @ W2 + b2 + BN1(Y)
    f32x4 acc2[2][4];
#pragma unroll
    for (int i = 0; i < 2; i++)
#pragma unroll
        for (int j = 0; j < 4; j++) acc2[i][j] = (f32x4){0.f, 0.f, 0.f, 0.f};
#pragma unroll
    for (int ks = 0; ks < 8; ks++) {
        int k0 = ks * 32 + quad * 8;
        bfrag8 a0 = *(const bfrag8*)&Zs[wr * 32 + l15][k0];
        bfrag8 a1 = *(const bfrag8*)&Zs[wr * 32 + 16 + l15][k0];
#pragma unroll
        for (int jn = 0; jn < 4; jn++) {
            int nt = wc * 4 + jn;
            bfrag8 b = *(const bfrag8*)(W2p + (((size_t)nt * 8 + ks) * 64 + lane) * 8);
            acc2[0][jn] = __builtin_amdgcn_mfma_f32_16x16x32_bf16(a0, b, acc2[0][jn], 0, 0, 0);
            acc2[1][jn] = __builtin_amdgcn_mfma_f32_16x16x32_bf16(a1, b, acc2[1][jn], 0, 0, 0);
        }
    }
    __syncthreads();  // Zs reads done -> reuse as T bounce

    unsigned short(*Ts)[136] = (unsigned short(*)[136]) & Zs[0][0];
    float colS[4] = {0.f, 0.f, 0.f, 0.f}, colQ[4] = {0.f, 0.f, 0.f, 0.f};
#pragma unroll
    for (int i = 0; i < 2; i++) {
        int rb = wr * 32 + i * 16 + quad * 4;
#pragma unroll
        for (int jn = 0; jn < 4; jn++) {
            int cl = wc * 64 + jn * 16 + l15;
            float s1v = Cf[cl], sh1v = Cf[128 + cl], b2v = Cf[512 + cl];
#pragma unroll
            for (int r = 0; r < 4; r++) {
                int rl = rb + r;
                float yv = b2f(As[rl][cl]);
                float v = acc2[i][jn][r] + b2v + yv * s1v + sh1v;
                Ts[rl][cl] = f2b(v);
                if (row0 + rl < N) {
                    colS[jn] += v;
                    colQ[jn] += v * v;
                }
            }
        }
    }
    __syncthreads();  // Ts writes + all Cf reads done
    Cf[tid] = 0.f;
    __syncthreads();
#pragma unroll
    for (int jn = 0; jn < 4; jn++) {
        float s = colS[jn], q = colQ[jn];
        s += __shfl_xor(s, 16, 64);
        q += __shfl_xor(q, 16, 64);
        s += __shfl_xor(s, 32, 64);
        q += __shfl_xor(q, 32, 64);
        if (quad == 0) {
            int cl = wc * 64 + jn * 16 + l15;
            atomicAdd(&Cf[cl], s);
            atomicAdd(&Cf[128 + cl], q);
        }
    }
    __syncthreads();
    atomicAdd(&bank2[(size_t)(blockIdx.x & (NBANK - 1)) * 256 + tid], Cf[tid]);
#pragma unroll
    for (int j = 0; j < 4; j++) {
        int idx = tid + j * 256;
        int u = idx >> 4, col8 = (idx & 15) * 8;
        int grow = row0 + u;
        if (grow < N) *(uint4*)(Tb + (size_t)grow * 128 + col8) = *(const uint4*)&Ts[u][col8];
    }
}

__global__ void bnfin2_k(const float* __restrict__ bank2,
                         const float* __restrict__ g, const float* __restrict__ be,
                         float* __restrict__ ss) {
    __shared__ float sm[256];
    int t = threadIdx.x;
    float s = 0.f;
    for (int cp = 0; cp < NBANK; cp++) s += bank2[cp * 256 + t];
    sm[t] = s;
    __syncthreads();
    if (t < 128) {
        float mu = sm[t] * (1.f / N);
        float var = sm[128 + t] * (1.f / N) - mu * mu;
        float sc = g[t] * rsqrtf(var + 1e-5f);
        ss[t] = sc;
        ss[128 + t] = be[t] - mu * sc;
    }
}

__global__ void bnout_k(const unsigned short* __restrict__ T, const float* __restrict__ ss,
                        float* __restrict__ Out) {
    size_t idx = ((size_t)blockIdx.x * 256 + threadIdx.x) * 8;
    if (idx >= (size_t)N * 128) return;
    int c0 = (int)(idx & 127);
    uint4 tv = *(const uint4*)(T + idx);
    float f[8];
    f[0] = __uint_as_float(tv.x << 16);
    f[1] = __uint_as_float(tv.x & 0xFFFF0000u);
    f[2] = __uint_as_float(tv.y << 16);
    f[3] = __uint_as_float(tv.y & 0xFFFF0000u);
    f[4] = __uint_as_float(tv.z << 16);
    f[5] = __uint_as_float(tv.z & 0xFFFF0000u);
    f[6] = __uint_as_float(tv.w << 16);
    f[7] = __uint_as_float(tv.w & 0xFFFF0000u);
    float4 o0, o1;
    o0.x = f[0] * ss[c0 + 0] + ss[128 + c0 + 0];
    o0.y = f[1] * ss[c0 + 1] + ss[128 + c0 + 1];
    o0.z = f[2] * ss[c0 + 2] + ss[128 + c0 + 2];
    o0.w = f[3] * ss[c0 + 3] + ss[128 + c0 + 3];
    o1.x = f[4] * ss[c0 + 4] + ss[128 + c0 + 4];
    o1.y = f[5] * ss[c0 + 5] + ss[128 + c0 + 5];
    o1.z = f[6] * ss[c0 + 6] + ss[128 + c0 + 6];
    o1.w = f[7] * ss[c0 + 7] + ss[128 + c0 + 7];
    *(float4*)(Out + idx) = o0;
    *(float4*)(Out + idx + 4) = o1;
}

extern "C" void kernel_launch(void* const* d_in, const int* in_sizes, int n_in,
                              void* d_out, int out_size, void* d_ws, size_t ws_size,
                              hipStream_t stream) {
    const float* x = (const float*)d_in[0];
    const int* eidx = (const int*)d_in[1];
    const float* WQ = (const float*)d_in[2];
    const float* WK = (const float*)d_in[3];
    const float* WV = (const float*)d_in[4];
    const float* WO = (const float*)d_in[5];
    const float* bO = (const float*)d_in[6];
    const float* W1 = (const float*)d_in[7];
    const float* b1 = (const float*)d_in[8];
    const float* W2 = (const float*)d_in[9];
    const float* b2 = (const float*)d_in[10];
    const float* g1 = (const float*)d_in[11];
    const float* be1 = (const float*)d_in[12];
    const float* g2 = (const float*)d_in[13];
    const float* be2 = (const float*)d_in[14];
    float* out = (float*)d_out;

    char* ws = (char*)d_ws;
    int* counts = (int*)(ws + OFF_COUNTS);
    int* cursors = (int*)(ws + OFF_CURSORS);
    float* bank1 = (float*)(ws + OFF_BANK1);
    float* bank2 = (float*)(ws + OFF_BANK2);
    int* done = (int*)(ws + OFF_DONE);
    int* offs = (int*)(ws + OFF_OFFS);
    int* bsum = (int*)(ws + OFF_BSUM);
    int* bpref = (int*)(ws + OFF_BPREF);
    float* ss1 = (float*)(ws + OFF_SS1);
    float* ss2 = (float*)(ws + OFF_SS2);
    float* b1p = (float*)(ws + OFF_B1P);
    int* csr = (int*)(ws + OFF_CSR);
    unsigned short* WQKVp = (unsigned short*)(ws + OFF_WQKVP);
    unsigned short* WOp = (unsigned short*)(ws + OFF_WOP);
    float* W1pf = (float*)(ws + OFF_W1PF);
    unsigned short* W1p = (unsigned short*)(ws + OFF_W1P);
    unsigned short* W2p = (unsigned short*)(ws + OFF_W2P);
    unsigned short* qb = (unsigned short*)(ws + OFF_Q);
    unsigned short* kv = (unsigned short*)(ws + OFF_KV);
    unsigned short* agg = (unsigned short*)(ws + OFF_AGG);
    unsigned short* Yb = (unsigned short*)(ws + OFF_Y);
    unsigned short* Tb = (unsigned short*)(ws + OFF_T);
    unsigned short* xb = (unsigned short*)(ws + OFF_XB);

    const int ZB = (int)((ZW + 255) / 256);  // zeroing blocks
    prep_w<<<512 + ZB, 256, 0, stream>>>(WQ, WK, WV, WO, W1, W2, WQKVp, WOp, W1pf, W2p,
                                         (unsigned*)ws);

    const int EB = (E + 255) / 256;  // 1954
    const int MB64 = (N + 63) / 64;  // 782
    // qkv + edge histogram in one dispatch (both depend only on prep_w)
    qkv_k<<<MB64 + EB, 256, 0, stream>>>(x, WQKVp, qb, kv, xb, eidx, counts, MB64);
    scan_a<<<196, 256, 0, stream>>>(counts, offs, bsum, bpref, done);
    fill_k<<<EB, 256, 0, stream>>>(eidx, offs, bpref, cursors, csr);
    attn_k<<<(N + 3) / 4, 256, 0, stream>>>(qb, kv, csr, offs, bpref, counts, agg);
    wo_k<<<MB64, 256, 0, stream>>>(agg, WOp, xb, bO, Yb, bank1);
    bnscale_k<<<128, 256, 0, stream>>>(bank1, g1, be1, W1, b1, W1pf, ss1, b1p, W1p);
    ffn_k<<<MB64, 256, 0, stream>>>(Yb, W1p, W2p, ss1, b1p, b2, Tb, bank2);
    bnfin2_k<<<1, 256, 0, stream>>>(bank2, g2, be2, ss2);
    bnout_k<<<(int)(((size_t)N * 128 / 8 + 255) / 256), 256, 0, stream>>>(Tb, ss2, out);
}